// Round 3
// baseline (9469.559 us; speedup 1.0000x reference)
//
#include <hip/hip_runtime.h>
#include <stdint.h>

#define SEQ    128
#define BATCH  16
#define EMBED  1024
#define HIDDEN 1024
#define VOCAB  50257
#define TB     (SEQ*BATCH)   /* 2048 */
#define G4     (4*HIDDEN)    /* 4096 */

typedef __bf16 bf16x8 __attribute__((ext_vector_type(8)));
typedef float  f32x4  __attribute__((ext_vector_type(4)));

__device__ __forceinline__ unsigned short f2bf(float f) {
  unsigned x = __float_as_uint(f);
  return (unsigned short)((x + 0x7FFFu + ((x >> 16) & 1u)) >> 16);
}

// ---------------- f32 -> bf16 bulk convert (n4 = n/4 float4 groups) ----------
__global__ __launch_bounds__(256) void k_f32_to_bf16(
    const float* __restrict__ src, unsigned short* __restrict__ dst, int n4) {
  int i = blockIdx.x * 256 + threadIdx.x;
  if (i >= n4) return;
  float4 v = reinterpret_cast<const float4*>(src)[i];
  ushort4 o;
  o.x = f2bf(v.x); o.y = f2bf(v.y); o.z = f2bf(v.z); o.w = f2bf(v.w);
  reinterpret_cast<ushort4*>(dst)[i] = o;
}

// ---------------- embedding gather -> bf16, grid(TB) x 256 -------------------
__global__ __launch_bounds__(256) void k_gather(
    const int* __restrict__ tokens, const float* __restrict__ emb,
    unsigned short* __restrict__ x) {
  int r = blockIdx.x;
  int tok = tokens[r];
  float4 v = reinterpret_cast<const float4*>(emb + (size_t)tok * EMBED)[threadIdx.x];
  ushort4 o;
  o.x = f2bf(v.x); o.y = f2bf(v.y); o.z = f2bf(v.z); o.w = f2bf(v.w);
  reinterpret_cast<ushort4*>(x + (size_t)r * EMBED)[threadIdx.x] = o;
}

// ---------------- bf16 GEMM: C(M,N) = A(M,K) * B(N,K)^T + bias ---------------
// 128x128 tile, BK=32, 4 waves (2x2), each wave 4x4 frags of 16x16x32 MFMA.
__global__ __launch_bounds__(256) void k_gemm_bt(
    const unsigned short* __restrict__ A, const unsigned short* __restrict__ B,
    float* __restrict__ C, const float* __restrict__ bias1,
    const float* __restrict__ bias2, int M, int N, int K) {
  __shared__ unsigned short Asm[128 * 32];
  __shared__ unsigned short Bsm[128 * 32];
  const int tid  = threadIdx.x;
  const int lane = tid & 63;
  const int wave = tid >> 6;
  const int wr = wave >> 1, wc = wave & 1;
  const int tile_m = blockIdx.y * 128;
  const int tile_n = blockIdx.x * 128;

  f32x4 acc[4][4];
  for (int m = 0; m < 4; ++m)
    for (int n = 0; n < 4; ++n)
      acc[m][n] = (f32x4){0.f, 0.f, 0.f, 0.f};

  const int sr = tid >> 2;          // 0..63
  const int sc = (tid & 3) << 3;    // 0,8,16,24
  const int fr = lane & 15;
  const int kk = (lane >> 4) << 3;  // 0,8,16,24

  for (int kt = 0; kt < K; kt += 32) {
    // stage A (rows always in-bounds: M multiple of 128)
    *reinterpret_cast<uint4*>(&Asm[sr * 32 + sc]) =
        *reinterpret_cast<const uint4*>(A + (size_t)(tile_m + sr) * K + kt + sc);
    *reinterpret_cast<uint4*>(&Asm[(64 + sr) * 32 + sc]) =
        *reinterpret_cast<const uint4*>(A + (size_t)(tile_m + 64 + sr) * K + kt + sc);
    // stage B with N bounds (zero-fill)
    uint4 v0 = {0, 0, 0, 0}, v1 = {0, 0, 0, 0};
    int r0 = tile_n + sr, r1 = tile_n + 64 + sr;
    if (r0 < N) v0 = *reinterpret_cast<const uint4*>(B + (size_t)r0 * K + kt + sc);
    if (r1 < N) v1 = *reinterpret_cast<const uint4*>(B + (size_t)r1 * K + kt + sc);
    *reinterpret_cast<uint4*>(&Bsm[sr * 32 + sc]) = v0;
    *reinterpret_cast<uint4*>(&Bsm[(64 + sr) * 32 + sc]) = v1;
    __syncthreads();

    bf16x8 a[4], b[4];
    for (int m = 0; m < 4; ++m)
      a[m] = *reinterpret_cast<const bf16x8*>(&Asm[(wr * 64 + m * 16 + fr) * 32 + kk]);
    for (int n = 0; n < 4; ++n)
      b[n] = *reinterpret_cast<const bf16x8*>(&Bsm[(wc * 64 + n * 16 + fr) * 32 + kk]);
    for (int m = 0; m < 4; ++m)
      for (int n = 0; n < 4; ++n)
        acc[m][n] = __builtin_amdgcn_mfma_f32_16x16x32_bf16(a[m], b[n], acc[m][n], 0, 0, 0);
    __syncthreads();
  }

  const int fq = lane >> 4;
  for (int n = 0; n < 4; ++n) {
    int col = tile_n + wc * 64 + n * 16 + fr;
    if (col >= N) continue;
    float bs = 0.f;
    if (bias1) bs += bias1[col];
    if (bias2) bs += bias2[col];
    for (int m = 0; m < 4; ++m) {
      int row = tile_m + wr * 64 + m * 16 + fq * 4;
      for (int j = 0; j < 4; ++j)
        C[(size_t)(row + j) * N + col] = acc[m][n][j] + bs;
    }
  }
}

// ---------------- one LSTM timestep ------------------------------------------
// grid 256 x 256. Block bk covers hidden slice jh in [bk*4, bk*4+4), all 4 gates,
// all 16 batches. Thread: one dot of length 1024 (fp32).
__global__ __launch_bounds__(256) void k_lstm_step(
    const float* __restrict__ xg,    // (TB, 4096), rows t*16+b
    const float* __restrict__ w_hh,  // (4096, 1024) f32
    float* __restrict__ h_state,     // (16, 1024)
    float* __restrict__ c_state,     // (16, 1024)
    unsigned short* __restrict__ h_all,  // (TB, 1024) bf16
    int t) {
  __shared__ float h_lds[16 * 1024];  // viewed as [16][256] float4, rotated by b
  const int tid = threadIdx.x;

  // stage h into LDS (float4-rotated per row: bank-conflict-free broadcast reads)
  float4* h_lds4 = reinterpret_cast<float4*>(h_lds);
  const float4* hs4 = reinterpret_cast<const float4*>(h_state);
  for (int i = 0; i < 16; ++i)
    h_lds4[i * 256 + ((tid + i) & 255)] = hs4[i * 256 + tid];
  __syncthreads();

  const int b  = tid >> 4;   // 0..15
  const int gj = tid & 15;   // g*4 + jl
  const int g  = gj >> 2;
  const int jl = gj & 3;
  const int j  = g * HIDDEN + blockIdx.x * 4 + jl;  // w_hh row
  const float4* w4 = reinterpret_cast<const float4*>(w_hh + (size_t)j * HIDDEN);

  float acc = 0.f;
#pragma unroll 8
  for (int k = 0; k < 256; ++k) {
    float4 hv = h_lds4[b * 256 + ((k + b) & 255)];
    float4 wv = w4[k];
    acc += hv.x * wv.x + hv.y * wv.y + hv.z * wv.z + hv.w * wv.w;
  }
  acc += xg[(size_t)(t * 16 + b) * G4 + j];
  __syncthreads();                 // done reading h_lds; reuse it for gates
  h_lds[b * 16 + gj] = acc;
  __syncthreads();

  if (tid < 64) {
    int bb = tid >> 2;
    int jj = tid & 3;
    int jh = blockIdx.x * 4 + jj;
    float vi = h_lds[bb * 16 + 0  + jj];
    float vf = h_lds[bb * 16 + 4  + jj];
    float vg = h_lds[bb * 16 + 8  + jj];
    float vo = h_lds[bb * 16 + 12 + jj];
    float c_old = c_state[bb * HIDDEN + jh];
    float si = 1.f / (1.f + __expf(-vi));
    float sf = 1.f / (1.f + __expf(-vf));
    float so = 1.f / (1.f + __expf(-vo));
    float c = sf * c_old + si * tanhf(vg);
    float h = so * tanhf(c);
    c_state[bb * HIDDEN + jh] = c;
    h_state[bb * HIDDEN + jh] = h;
    h_all[(size_t)(t * 16 + bb) * HIDDEN + jh] = f2bf(h);
  }
}

// ---------------- log-softmax: per-row online (max, sumexp) ------------------
__global__ __launch_bounds__(256) void k_ls_reduce(
    const float* __restrict__ logits, float* __restrict__ rowa) {
  __shared__ float ms[256], ls[256];
  const int tid = threadIdx.x;
  const float* row = logits + (size_t)blockIdx.x * VOCAB;
  float m = -3.4e38f, l = 0.f;
  for (int i = tid; i < VOCAB; i += 256) {
    float v = row[i];
    float nm = fmaxf(m, v);
    l = l * __expf(m - nm) + __expf(v - nm);
    m = nm;
  }
  ms[tid] = m; ls[tid] = l;
  __syncthreads();
  for (int s = 128; s > 0; s >>= 1) {
    if (tid < s) {
      float m2 = ms[tid + s], l2 = ls[tid + s];
      float nm = fmaxf(ms[tid], m2);
      ls[tid] = ls[tid] * __expf(ms[tid] - nm) + l2 * __expf(m2 - nm);
      ms[tid] = nm;
    }
    __syncthreads();
  }
  if (tid == 0) rowa[blockIdx.x] = ms[0] + logf(ls[0]);
}

__global__ __launch_bounds__(256) void k_ls_finalize(
    float* __restrict__ out, const float* __restrict__ rowa) {
  unsigned i4 = blockIdx.x * 256 + threadIdx.x;
  float4 v = reinterpret_cast<float4*>(out)[i4];
  unsigned base = i4 * 4u;
  v.x -= rowa[(base + 0u) / VOCAB];
  v.y -= rowa[(base + 1u) / VOCAB];
  v.z -= rowa[(base + 2u) / VOCAB];
  v.w -= rowa[(base + 3u) / VOCAB];
  reinterpret_cast<float4*>(out)[i4] = v;
}

// ---------------- workspace layout (bytes) -----------------------------------
#define OFF_WOUT   ((size_t)0)                       // VOCAB*1024 bf16 = 102,926,336
#define OFF_WIH0   (OFF_WOUT + (size_t)VOCAB*1024*2) // 8,388,608
#define OFF_WIH1   (OFF_WIH0 + (size_t)G4*1024*2)
#define OFF_X0     (OFF_WIH1 + (size_t)G4*1024*2)    // TB*1024 bf16
#define OFF_H0ALL  (OFF_X0   + (size_t)TB*1024*2)
#define OFF_H1ALL  (OFF_H0ALL+ (size_t)TB*1024*2)
#define OFF_XG     (OFF_H1ALL+ (size_t)TB*1024*2)    // TB*4096 f32 = 33,554,432
#define OFF_HSTATE (OFF_XG   + (size_t)TB*G4*4)      // 16*1024 f32
#define OFF_CSTATE (OFF_HSTATE + (size_t)16*1024*4)
#define OFF_ROWA   (OFF_CSTATE + (size_t)16*1024*4)  // TB f32

extern "C" void kernel_launch(void* const* d_in, const int* in_sizes, int n_in,
                              void* d_out, int out_size, void* d_ws, size_t ws_size,
                              hipStream_t stream) {
  (void)in_sizes; (void)n_in; (void)out_size; (void)ws_size;
  const int*   tokens = (const int*)d_in[0];
  const float* emb    = (const float*)d_in[1];
  const float* w_ih0  = (const float*)d_in[2];
  const float* w_hh0  = (const float*)d_in[3];
  const float* b_ih0  = (const float*)d_in[4];
  const float* b_hh0  = (const float*)d_in[5];
  const float* w_ih1  = (const float*)d_in[6];
  const float* w_hh1  = (const float*)d_in[7];
  const float* b_ih1  = (const float*)d_in[8];
  const float* b_hh1  = (const float*)d_in[9];
  const float* W_out  = (const float*)d_in[10];
  const float* b_out  = (const float*)d_in[11];

  char* ws = (char*)d_ws;
  unsigned short* Wout_bf = (unsigned short*)(ws + OFF_WOUT);
  unsigned short* wih0_bf = (unsigned short*)(ws + OFF_WIH0);
  unsigned short* wih1_bf = (unsigned short*)(ws + OFF_WIH1);
  unsigned short* x0      = (unsigned short*)(ws + OFF_X0);
  unsigned short* h0all   = (unsigned short*)(ws + OFF_H0ALL);
  unsigned short* h1all   = (unsigned short*)(ws + OFF_H1ALL);
  float* xg      = (float*)(ws + OFF_XG);
  float* h_state = (float*)(ws + OFF_HSTATE);
  float* c_state = (float*)(ws + OFF_CSTATE);
  float* rowa    = (float*)(ws + OFF_ROWA);
  float* out     = (float*)d_out;

  // 1. weight conversions to bf16
  k_f32_to_bf16<<<dim3(VOCAB * 1024 / 4 / 256), 256, 0, stream>>>(W_out, Wout_bf, VOCAB * 1024 / 4);
  k_f32_to_bf16<<<dim3(G4 * 1024 / 4 / 256), 256, 0, stream>>>(w_ih0, wih0_bf, G4 * 1024 / 4);
  k_f32_to_bf16<<<dim3(G4 * 1024 / 4 / 256), 256, 0, stream>>>(w_ih1, wih1_bf, G4 * 1024 / 4);

  // 2. embedding gather
  k_gather<<<dim3(TB), 256, 0, stream>>>(tokens, emb, x0);

  // 3. layer 0: input projection, then 128 recurrence steps
  hipMemsetAsync(h_state, 0, 2 * 16 * 1024 * sizeof(float), stream);  // h + c
  k_gemm_bt<<<dim3(G4 / 128, TB / 128), 256, 0, stream>>>(
      x0, wih0_bf, xg, b_ih0, b_hh0, TB, G4, EMBED);
  for (int t = 0; t < SEQ; ++t)
    k_lstm_step<<<dim3(256), 256, 0, stream>>>(xg, w_hh0, h_state, c_state, h0all, t);

  // 4. layer 1
  hipMemsetAsync(h_state, 0, 2 * 16 * 1024 * sizeof(float), stream);
  k_gemm_bt<<<dim3(G4 / 128, TB / 128), 256, 0, stream>>>(
      h0all, wih1_bf, xg, b_ih1, b_hh1, TB, G4, HIDDEN);
  for (int t = 0; t < SEQ; ++t)
    k_lstm_step<<<dim3(256), 256, 0, stream>>>(xg, w_hh1, h_state, c_state, h1all, t);

  // 5. output projection -> logits (in d_out)
  k_gemm_bt<<<dim3((VOCAB + 127) / 128, TB / 128), 256, 0, stream>>>(
      h1all, Wout_bf, out, b_out, nullptr, TB, VOCAB, HIDDEN);

  // 6. log-softmax in place
  k_ls_reduce<<<dim3(TB), 256, 0, stream>>>(out, rowa);
  k_ls_finalize<<<dim3((unsigned)((size_t)TB * VOCAB / 4 / 256)), 256, 0, stream>>>(out, rowa);
}